// Round 5
// baseline (142.978 us; speedup 1.0000x reference)
//
#include <hip/hip_runtime.h>
#include <math.h>

// Geometry fixed by reference: (B=2, T=20, H=480, W=480)
#define TS   20
#define NL   5
#define NS   26    // [0..4]=hits [5..9]=p_tot [10..14]=t_tot [15..19]=mae_cum [20]=cnt [21..25]=Sp,St,Spt,Spp,Stt
#define GX   45
#define TPB  256
#define F4PT 5     // float4 per thread: 45*256*5 = 57600 exactly
#define HW4  57600

// thresholds mapped to normalized space: p >= thr  <=>  pn >= ln(thr+1)/ln(31)
constexpr float C1 = (float)(0.09531017980432486 / 3.4339872044851463);
constexpr float C2 = (float)(0.69314718055994531 / 3.4339872044851463);
constexpr float C3 = (float)(1.09861228866810969 / 3.4339872044851463);
constexpr float C4 = (float)(1.79175946922805500 / 3.4339872044851463);
constexpr float C5 = (float)(2.19722457733621938 / 3.4339872044851463);

__device__ __forceinline__ float expm1_ln31(float x)   // exp(x*ln31) - 1, x in [0,1)
{
#if __has_builtin(__builtin_amdgcn_exp2f)
    return __builtin_amdgcn_exp2f(x * 4.9541963103868751f) - 1.0f;  // ln(31)*log2(e)
#else
    return __expf(x * 3.4339872044851463f) - 1.0f;
#endif
}

__device__ __forceinline__ void px(float pn, float tn, float mn,
    unsigned& pP, unsigned& tP, unsigned& hP, int& cnt, float cum[NL],
    float& sp, float& st, float& spt, float& spp, float& stt)
{
    bool mok = mn > 0.5f;
    float pm = mok ? pn : -1.0f;                // fold mask: all compares fail when masked out
    float qm = mok ? tn : -1.0f;
    bool p1 = pm >= C1, p2 = pm >= C2, p3 = pm >= C3, p4 = pm >= C4, p5 = pm >= C5;
    bool q1 = qm >= C1, q2 = qm >= C2, q3 = qm >= C3, q4 = qm >= C4, q5 = qm >= C5;
    int lp = (int)p1 + (int)p2 + (int)p3 + (int)p4 + (int)p5;   // 0..5; 0 = below thr[0] or masked
    int lq = (int)q1 + (int)q2 + (int)q3 + (int)q4 + (int)q5;
    unsigned ohp = 1u << (5 * lp);
    pP += ohp;
    tP += 1u << (5 * lq);
    hP += (lp == lq) ? ohp : 0u;                // field 0 collects junk
    float p = expm1_ln31(pn);                   // physical values only feed moments / |p-q|
    float q = expm1_ln31(tn);
    bool cond = (lp | lq) != 0;                 // mask && !(double-zero)
    cnt += cond ? 1 : 0;
    float pz = cond ? p : 0.0f;
    float qz = cond ? q : 0.0f;
    sp += pz;  st += qz;
    spt = fmaf(pz, qz, spt);
    spp = fmaf(pz, pz, spp);
    stt = fmaf(qz, qz, stt);
    float ad = fabsf(p - q);
    cum[0] += q1 ? ad : 0.0f;                   // cumulative: mae_num[l] = cum[l] - cum[l+1]
    cum[1] += q2 ? ad : 0.0f;
    cum[2] += q3 ? ad : 0.0f;
    cum[3] += q4 ? ad : 0.0f;
    cum[4] += q5 ? ad : 0.0f;
}

__global__ __launch_bounds__(TPB) void metscore_pass1(
    const float4* __restrict__ pred, const float4* __restrict__ targ,
    const float4* __restrict__ mask, float* __restrict__ sums /* [TS][NS] */)
{
    const int t = blockIdx.y;
    const int b = blockIdx.z;
    const size_t base = ((size_t)b * TS + t) * (size_t)HW4
                      + (size_t)blockIdx.x * (F4PT * TPB) + threadIdx.x;

    // ---- issue ALL 15 loads back-to-back (no compute dependence) -> MLP = 15/wave ----
    float4 P[F4PT], T[F4PT], M[F4PT];
    #pragma unroll
    for (int j = 0; j < F4PT; ++j) P[j] = pred[base + j * TPB];
    #pragma unroll
    for (int j = 0; j < F4PT; ++j) T[j] = targ[base + j * TPB];
    #pragma unroll
    for (int j = 0; j < F4PT; ++j) M[j] = mask[base + j * TPB];

    unsigned pP = 0u, tP = 0u, hP = 0u;
    int cnt = 0;
    float cum[NL] = {0, 0, 0, 0, 0};
    float sp = 0, st = 0, spt = 0, spp = 0, stt = 0;

    #pragma unroll
    for (int j = 0; j < F4PT; ++j) {
        px(P[j].x, T[j].x, M[j].x, pP, tP, hP, cnt, cum, sp, st, spt, spp, stt);
        px(P[j].y, T[j].y, M[j].y, pP, tP, hP, cnt, cum, sp, st, spt, spp, stt);
        px(P[j].z, T[j].z, M[j].z, pP, tP, hP, cnt, cum, sp, st, spt, spp, stt);
        px(P[j].w, T[j].w, M[j].w, pP, tP, hP, cnt, cum, sp, st, spt, spp, stt);
    }

    // drain one-hot packs (20 px < 31 field capacity) into 2x16-bit packed accumulators
    unsigned c16[8];
    #pragma unroll
    for (int k = 0; k < 8; ++k) c16[k] = 0u;
    #pragma unroll
    for (int l = 0; l < NL; ++l) {
        c16[l >> 1]        += ((hP >> (5 * (l + 1))) & 31u) << (16 * (l & 1));
        c16[(5 + l) >> 1]  += ((pP >> (5 * (l + 1))) & 31u) << (16 * ((5 + l) & 1));
        c16[(10 + l) >> 1] += ((tP >> (5 * (l + 1))) & 31u) << (16 * ((10 + l) & 1));
    }
    c16[7] += (unsigned)cnt << 16;   // counter 15 = cnt (<=20/thread; block <=5120 < 32768)

    // wave(64) reduce: 8 packed u32 + 10 floats
    float f[10] = {cum[0], cum[1], cum[2], cum[3], cum[4], sp, st, spt, spp, stt};
    #pragma unroll
    for (int k = 0; k < 8; ++k) {
        unsigned x = c16[k];
        x += __shfl_down(x, 32); x += __shfl_down(x, 16); x += __shfl_down(x, 8);
        x += __shfl_down(x, 4);  x += __shfl_down(x, 2);  x += __shfl_down(x, 1);
        c16[k] = x;
    }
    #pragma unroll
    for (int k = 0; k < 10; ++k) {
        float x = f[k];
        x += __shfl_down(x, 32); x += __shfl_down(x, 16); x += __shfl_down(x, 8);
        x += __shfl_down(x, 4);  x += __shfl_down(x, 2);  x += __shfl_down(x, 1);
        f[k] = x;
    }

    __shared__ unsigned ldsU[4][8];
    __shared__ float    ldsF[4][10];
    const int lane = threadIdx.x & 63;
    const int wv   = threadIdx.x >> 6;
    if (lane == 0) {
        #pragma unroll
        for (int k = 0; k < 8; ++k) ldsU[wv][k] = c16[k];
        #pragma unroll
        for (int k = 0; k < 10; ++k) ldsF[wv][k] = f[k];
    }
    __syncthreads();
    if (threadIdx.x < 8) {
        unsigned s = ldsU[0][threadIdx.x] + ldsU[1][threadIdx.x]
                   + ldsU[2][threadIdx.x] + ldsU[3][threadIdx.x];
        int c0 = 2 * threadIdx.x, c1 = c0 + 1;          // counter indices
        int n0 = (c0 == 15) ? 20 : c0;                  // counter->NS slot (cnt lives at 20)
        int n1 = (c1 == 15) ? 20 : c1;
        atomicAdd(&sums[t * NS + n0], (float)(s & 0xFFFFu));
        atomicAdd(&sums[t * NS + n1], (float)(s >> 16));
    } else if (threadIdx.x < 18) {
        int k = threadIdx.x - 8;                        // 0..4 cum -> 15..19, 5..9 moments -> 21..25
        float s = ldsF[0][k] + ldsF[1][k] + ldsF[2][k] + ldsF[3][k];
        int n = (k < 5) ? (15 + k) : (16 + k);
        atomicAdd(&sums[t * NS + n], s);
    }
}

// out layout: [0]=total [1..20]=score_time [21..40]=r_time [41..140]=ts_mat
//             [141..240]=mae_mat [241..245]=ts mean [246..250]=mae mean
__global__ __launch_bounds__(128) void metscore_final(
    const float* __restrict__ sums, float* __restrict__ out)
{
    __shared__ float ts_s[TS][NL];
    __shared__ float mae_s[TS][NL];
    __shared__ float sc_s[TS];
    const int tid = threadIdx.x;

    if (tid < TS * NL) {
        int tt_ = tid / NL, l = tid % NL;
        const float* s = sums + tt_ * NS;
        float h = s[l], pt = s[5 + l], tt = s[10 + l];
        float mn = s[15 + l] - ((l < NL - 1) ? s[16 + l] : 0.0f);   // telescoped mae_num
        float ts  = h / (pt + tt - h + 1e-8f);
        float mae = (tt > 0.0f) ? (mn / fmaxf(tt, 1.0f)) : 0.0f;
        ts_s[tt_][l]  = ts;
        mae_s[tt_][l] = mae;
        out[41 + tid]  = ts;
        out[141 + tid] = mae;
    }
    __syncthreads();

    if (tid < TS) {
        const float* s = sums + tid * NS;
        double cnt = s[20], sp = s[21], st = s[22];
        double spt = s[23], spp = s[24], stt = s[25];
        double sc = fmax(cnt, 1.0);
        double pmn = sp / sc, tmn = st / sc;
        double num = spt - pmn * st - tmn * sp + pmn * tmn * cnt;
        double vp  = spp - 2.0 * pmn * sp + pmn * pmn * cnt;
        double vt  = stt - 2.0 * tmn * st + tmn * tmn * cnt;
        double r = num / (sqrt(vp * vt) + 1e-6);
        r = fmin(fmax(r, -1.0), 1.0);
        float rt = (cnt > 0.0) ? (float)r : 0.0f;
        out[21 + tid] = rt;

        const float LW[NL] = {0.1f, 0.1f, 0.2f, 0.25f, 0.35f};
        float term_corr = sqrtf(expf(rt - 1.0f));
        float accl = 0.0f;
        #pragma unroll
        for (int l = 0; l < NL; ++l)
            accl += LW[l] * ts_s[tid][l] * sqrtf(expf(-mae_s[tid][l] * 0.01f));
        float sct = term_corr * accl;
        out[1 + tid] = sct;

        const float TW[TS] = {0.0075f, 0.02f, 0.03f, 0.04f, 0.05f, 0.06f, 0.07f,
                              0.08f, 0.09f, 0.1f, 0.09f, 0.08f, 0.07f, 0.06f,
                              0.05f, 0.04f, 0.03f, 0.02f, 0.0075f, 0.005f};
        sc_s[tid] = sct * TW[tid];
    }
    __syncthreads();

    if (tid == 0) {
        float tot = 0.0f;
        for (int k = 0; k < TS; ++k) tot += sc_s[k];
        out[0] = tot;
    }
    if (tid < NL) {
        float a = 0.0f, bsum = 0.0f;
        for (int k = 0; k < TS; ++k) { a += ts_s[k][tid]; bsum += mae_s[k][tid]; }
        out[241 + tid] = a * (1.0f / TS);
        out[246 + tid] = bsum * (1.0f / TS);
    }
}

extern "C" void kernel_launch(void* const* d_in, const int* in_sizes, int n_in,
                              void* d_out, int out_size, void* d_ws, size_t ws_size,
                              hipStream_t stream) {
    (void)in_sizes; (void)n_in; (void)out_size; (void)ws_size;
    const float4* pred = (const float4*)d_in[0];
    const float4* targ = (const float4*)d_in[1];
    const float4* mask = (const float4*)d_in[2];
    float* out  = (float*)d_out;
    float* sums = (float*)d_ws;

    // ws is poisoned 0xAA before every launch — zero the accumulators
    hipMemsetAsync(sums, 0, TS * NS * sizeof(float), stream);

    dim3 grid(GX, TS, 2);   // 1800 blocks -> ~7 blocks/CU resident
    metscore_pass1<<<grid, TPB, 0, stream>>>(pred, targ, mask, sums);
    metscore_final<<<1, 128, 0, stream>>>(sums, out);
}

// Round 7
// 137.445 us; speedup vs baseline: 1.0403x; 1.0403x over previous
//
#include <hip/hip_runtime.h>
#include <math.h>

// Geometry fixed by reference: (B=2, T=20, H=480, W=480)
#define TS   20
#define NL   5
#define NS   26    // [0..4]=hits [5..9]=p_tot [10..14]=t_tot [15..19]=mae_cum [20]=cnt [21..25]=Sp,St,Spt,Spp,Stt
#define GX   45
#define TPB  256
#define NWV  4     // waves per block
#define F4PT 5     // float4 stages per thread: 45*256*5 = 57600 exactly
#define HW4  57600

// thresholds mapped to normalized space: p >= thr  <=>  pn >= ln(thr+1)/ln(31)
constexpr float C1 = (float)(0.09531017980432486 / 3.4339872044851463);
constexpr float C2 = (float)(0.69314718055994531 / 3.4339872044851463);
constexpr float C3 = (float)(1.09861228866810969 / 3.4339872044851463);
constexpr float C4 = (float)(1.79175946922805500 / 3.4339872044851463);
constexpr float C5 = (float)(2.19722457733621938 / 3.4339872044851463);

// s_waitcnt imm (gfx9 encoding): vmcnt[3:0]=b3:0, expcnt=b6:4, lgkmcnt=b11:8, vmcnt[5:4]=b15:14
#define WAITCNT_VM3 0x0F73   // vmcnt<=3, ignore exp/lgkm
#define WAITCNT_VM0 0x0F70   // vmcnt<=0, ignore exp/lgkm

__device__ __forceinline__ void dma16(const void* g, void* l)
{
    __builtin_amdgcn_global_load_lds(
        (const __attribute__((address_space(1))) void*)g,
        (__attribute__((address_space(3))) void*)l, 16, 0, 0);
}

__device__ __forceinline__ float expm1_ln31(float x)   // exp(x*ln31) - 1, x in [0,1)
{
#if __has_builtin(__builtin_amdgcn_exp2f)
    return __builtin_amdgcn_exp2f(x * 4.9541963103868751f) - 1.0f;  // ln(31)*log2(e)
#else
    return __expf(x * 3.4339872044851463f) - 1.0f;
#endif
}

__device__ __forceinline__ void px(float pn, float tn, float mn,
    unsigned& pP, unsigned& tP, unsigned& hP, int& cnt, float cum[NL],
    float& sp, float& st, float& spt, float& spp, float& stt)
{
    bool mok = mn > 0.5f;
    float pm = mok ? pn : -1.0f;                // fold mask: all compares fail when masked out
    float qm = mok ? tn : -1.0f;
    bool p1 = pm >= C1, p2 = pm >= C2, p3 = pm >= C3, p4 = pm >= C4, p5 = pm >= C5;
    bool q1 = qm >= C1, q2 = qm >= C2, q3 = qm >= C3, q4 = qm >= C4, q5 = qm >= C5;
    int lp = (int)p1 + (int)p2 + (int)p3 + (int)p4 + (int)p5;   // 0..5; 0 = below thr[0] or masked
    int lq = (int)q1 + (int)q2 + (int)q3 + (int)q4 + (int)q5;
    unsigned ohp = 1u << (5 * lp);
    pP += ohp;
    tP += 1u << (5 * lq);
    hP += (lp == lq) ? ohp : 0u;                // field 0 collects junk
    float p = expm1_ln31(pn);                   // physical values only feed moments / |p-q|
    float q = expm1_ln31(tn);
    bool cond = (lp | lq) != 0;                 // mask && !(double-zero)
    cnt += cond ? 1 : 0;
    float pz = cond ? p : 0.0f;
    float qz = cond ? q : 0.0f;
    sp += pz;  st += qz;
    spt = fmaf(pz, qz, spt);
    spp = fmaf(pz, pz, spp);
    stt = fmaf(qz, qz, stt);
    float ad = fabsf(p - q);
    cum[0] += q1 ? ad : 0.0f;                   // cumulative: mae_num[l] = cum[l] - cum[l+1]
    cum[1] += q2 ? ad : 0.0f;
    cum[2] += q3 ? ad : 0.0f;
    cum[3] += q4 ? ad : 0.0f;
    cum[4] += q5 ? ad : 0.0f;
}

__global__ __launch_bounds__(TPB) void metscore_pass1(
    const float4* __restrict__ pred, const float4* __restrict__ targ,
    const float4* __restrict__ mask, float* __restrict__ sums /* [TS][NS] */)
{
    const int t = blockIdx.y;
    const int b = blockIdx.z;
    const int lane = threadIdx.x & 63;
    const int wv   = threadIdx.x >> 6;
    const size_t base = ((size_t)b * TS + t) * (size_t)HW4
                      + (size_t)blockIdx.x * (F4PT * TPB) + threadIdx.x;

    // per-wave private double-buffered staging: no __syncthreads anywhere in the hot loop
    __shared__ float4 buf[2][NWV][3][64];   // 24 KB

    // prologue: DMA stage 0 (3 x 1KB per wave, LDS dest = wave-uniform base + lane*16)
    dma16(&pred[base], &buf[0][wv][0][0]);
    dma16(&targ[base], &buf[0][wv][1][0]);
    dma16(&mask[base], &buf[0][wv][2][0]);

    unsigned pP = 0u, tP = 0u, hP = 0u;
    int cnt = 0;
    float cum[NL] = {0, 0, 0, 0, 0};
    float sp = 0, st = 0, spt = 0, spp = 0, stt = 0;

    #pragma unroll
    for (int s = 0; s < F4PT; ++s) {
        if (s + 1 < F4PT) {      // keep next stage's 3 DMAs in flight across this compute
            const int par = (s + 1) & 1;
            dma16(&pred[base + (s + 1) * TPB], &buf[par][wv][0][0]);
            dma16(&targ[base + (s + 1) * TPB], &buf[par][wv][1][0]);
            dma16(&mask[base + (s + 1) * TPB], &buf[par][wv][2][0]);
            __builtin_amdgcn_s_waitcnt(WAITCNT_VM3);   // stage s's DMAs done, s+1's in flight
        } else {
            __builtin_amdgcn_s_waitcnt(WAITCNT_VM0);
        }
        const int p0 = s & 1;
        float4 pv = buf[p0][wv][0][lane];
        float4 tv = buf[p0][wv][1][lane];
        float4 mv = buf[p0][wv][2][lane];
        px(pv.x, tv.x, mv.x, pP, tP, hP, cnt, cum, sp, st, spt, spp, stt);
        px(pv.y, tv.y, mv.y, pP, tP, hP, cnt, cum, sp, st, spt, spp, stt);
        px(pv.z, tv.z, mv.z, pP, tP, hP, cnt, cum, sp, st, spt, spp, stt);
        px(pv.w, tv.w, mv.w, pP, tP, hP, cnt, cum, sp, st, spt, spp, stt);
    }

    // drain one-hot packs (20 px < 31 field capacity) into 2x16-bit packed accumulators
    unsigned c16[8];
    #pragma unroll
    for (int k = 0; k < 8; ++k) c16[k] = 0u;
    #pragma unroll
    for (int l = 0; l < NL; ++l) {
        c16[l >> 1]        += ((hP >> (5 * (l + 1))) & 31u) << (16 * (l & 1));
        c16[(5 + l) >> 1]  += ((pP >> (5 * (l + 1))) & 31u) << (16 * ((5 + l) & 1));
        c16[(10 + l) >> 1] += ((tP >> (5 * (l + 1))) & 31u) << (16 * ((10 + l) & 1));
    }
    c16[7] += (unsigned)cnt << 16;   // counter 15 = cnt (<=20/thread; block <=5120 < 32768)

    // wave(64) reduce: 8 packed u32 + 10 floats
    float f[10] = {cum[0], cum[1], cum[2], cum[3], cum[4], sp, st, spt, spp, stt};
    #pragma unroll
    for (int k = 0; k < 8; ++k) {
        unsigned x = c16[k];
        x += __shfl_down(x, 32); x += __shfl_down(x, 16); x += __shfl_down(x, 8);
        x += __shfl_down(x, 4);  x += __shfl_down(x, 2);  x += __shfl_down(x, 1);
        c16[k] = x;
    }
    #pragma unroll
    for (int k = 0; k < 10; ++k) {
        float x = f[k];
        x += __shfl_down(x, 32); x += __shfl_down(x, 16); x += __shfl_down(x, 8);
        x += __shfl_down(x, 4);  x += __shfl_down(x, 2);  x += __shfl_down(x, 1);
        f[k] = x;
    }

    __shared__ unsigned ldsU[NWV][8];
    __shared__ float    ldsF[NWV][10];
    if (lane == 0) {
        #pragma unroll
        for (int k = 0; k < 8; ++k) ldsU[wv][k] = c16[k];
        #pragma unroll
        for (int k = 0; k < 10; ++k) ldsF[wv][k] = f[k];
    }
    __syncthreads();
    if (threadIdx.x < 8) {
        unsigned s = ldsU[0][threadIdx.x] + ldsU[1][threadIdx.x]
                   + ldsU[2][threadIdx.x] + ldsU[3][threadIdx.x];
        int c0 = 2 * threadIdx.x, c1 = c0 + 1;          // counter indices
        int n0 = (c0 == 15) ? 20 : c0;                  // counter->NS slot (cnt lives at 20)
        int n1 = (c1 == 15) ? 20 : c1;
        atomicAdd(&sums[t * NS + n0], (float)(s & 0xFFFFu));
        atomicAdd(&sums[t * NS + n1], (float)(s >> 16));
    } else if (threadIdx.x < 18) {
        int k = threadIdx.x - 8;                        // 0..4 cum -> 15..19, 5..9 moments -> 21..25
        float s = ldsF[0][k] + ldsF[1][k] + ldsF[2][k] + ldsF[3][k];
        int n = (k < 5) ? (15 + k) : (16 + k);
        atomicAdd(&sums[t * NS + n], s);
    }
}

// out layout: [0]=total [1..20]=score_time [21..40]=r_time [41..140]=ts_mat
//             [141..240]=mae_mat [241..245]=ts mean [246..250]=mae mean
__global__ __launch_bounds__(128) void metscore_final(
    const float* __restrict__ sums, float* __restrict__ out)
{
    __shared__ float ts_s[TS][NL];
    __shared__ float mae_s[TS][NL];
    __shared__ float sc_s[TS];
    const int tid = threadIdx.x;

    if (tid < TS * NL) {
        int tt_ = tid / NL, l = tid % NL;
        const float* s = sums + tt_ * NS;
        float h = s[l], pt = s[5 + l], tt = s[10 + l];
        float mn = s[15 + l] - ((l < NL - 1) ? s[16 + l] : 0.0f);   // telescoped mae_num
        float ts  = h / (pt + tt - h + 1e-8f);
        float mae = (tt > 0.0f) ? (mn / fmaxf(tt, 1.0f)) : 0.0f;
        ts_s[tt_][l]  = ts;
        mae_s[tt_][l] = mae;
        out[41 + tid]  = ts;
        out[141 + tid] = mae;
    }
    __syncthreads();

    if (tid < TS) {
        const float* s = sums + tid * NS;
        double cnt = s[20], sp = s[21], st = s[22];
        double spt = s[23], spp = s[24], stt = s[25];
        double sc = fmax(cnt, 1.0);
        double pmn = sp / sc, tmn = st / sc;
        double num = spt - pmn * st - tmn * sp + pmn * tmn * cnt;
        double vp  = spp - 2.0 * pmn * sp + pmn * pmn * cnt;
        double vt  = stt - 2.0 * tmn * st + tmn * tmn * cnt;
        double r = num / (sqrt(vp * vt) + 1e-6);
        r = fmin(fmax(r, -1.0), 1.0);
        float rt = (cnt > 0.0) ? (float)r : 0.0f;
        out[21 + tid] = rt;

        const float LW[NL] = {0.1f, 0.1f, 0.2f, 0.25f, 0.35f};
        float term_corr = sqrtf(expf(rt - 1.0f));
        float accl = 0.0f;
        #pragma unroll
        for (int l = 0; l < NL; ++l)
            accl += LW[l] * ts_s[tid][l] * sqrtf(expf(-mae_s[tid][l] * 0.01f));
        float sct = term_corr * accl;
        out[1 + tid] = sct;

        const float TW[TS] = {0.0075f, 0.02f, 0.03f, 0.04f, 0.05f, 0.06f, 0.07f,
                              0.08f, 0.09f, 0.1f, 0.09f, 0.08f, 0.07f, 0.06f,
                              0.05f, 0.04f, 0.03f, 0.02f, 0.0075f, 0.005f};
        sc_s[tid] = sct * TW[tid];
    }
    __syncthreads();

    if (tid == 0) {
        float tot = 0.0f;
        for (int k = 0; k < TS; ++k) tot += sc_s[k];
        out[0] = tot;
    }
    if (tid < NL) {
        float a = 0.0f, bsum = 0.0f;
        for (int k = 0; k < TS; ++k) { a += ts_s[k][tid]; bsum += mae_s[k][tid]; }
        out[241 + tid] = a * (1.0f / TS);
        out[246 + tid] = bsum * (1.0f / TS);
    }
}

extern "C" void kernel_launch(void* const* d_in, const int* in_sizes, int n_in,
                              void* d_out, int out_size, void* d_ws, size_t ws_size,
                              hipStream_t stream) {
    (void)in_sizes; (void)n_in; (void)out_size; (void)ws_size;
    const float4* pred = (const float4*)d_in[0];
    const float4* targ = (const float4*)d_in[1];
    const float4* mask = (const float4*)d_in[2];
    float* out  = (float*)d_out;
    float* sums = (float*)d_ws;

    // ws is poisoned 0xAA before every launch — zero the accumulators
    hipMemsetAsync(sums, 0, TS * NS * sizeof(float), stream);

    dim3 grid(GX, TS, 2);   // 1800 blocks; LDS caps residency at 6 blocks/CU (144/160 KB)
    metscore_pass1<<<grid, TPB, 0, stream>>>(pred, targ, mask, sums);
    metscore_final<<<1, 128, 0, stream>>>(sums, out);
}